// Round 1
// baseline (347.214 us; speedup 1.0000x reference)
//
#include <hip/hip_runtime.h>

#define N 16384
#define B 512
#define NNZ 131072
#define NITER 4   // R + 1

// ---------- math helpers ----------
__device__ __forceinline__ float sigmoid_(float x) {
    return 1.f / (1.f + __expf(-x));
}
__device__ __forceinline__ float tanh_(float x) {
    // overflow-safe: exp(2x)->inf gives 1, exp(2x)->0 gives -1
    return 1.f - 2.f / (__expf(2.f * x) + 1.f);
}

// ---------- index dtype detection ----------
// If indices are int64 (little-endian, values < 16384), every odd 32-bit word
// is a zero high word. If int32, odd words are random cols in [0,16384).
__global__ void detect_kernel(const int* __restrict__ w, int* __restrict__ flag) {
    if (blockIdx.x == 0 && threadIdx.x == 0) {
        int all0 = 1;
        for (int i = 1; i < 64; i += 2) all0 &= (w[i] == 0);
        *flag = all0;   // 1 => int64 layout, 0 => int32 layout
    }
}

__device__ __forceinline__ int dec_row(const int* w, int k, int is64) {
    return is64 ? w[4 * k]     : w[2 * k];
}
__device__ __forceinline__ int dec_col(const int* w, int k, int is64) {
    return is64 ? w[4 * k + 2] : w[2 * k + 1];
}

// ---------- CSC build ----------
__global__ void hist_kernel(const int* __restrict__ w, const int* __restrict__ flag,
                            int* __restrict__ counts) {
    int k = blockIdx.x * 256 + threadIdx.x;
    int is64 = *flag;
    int col = dec_col(w, k, is64);
    atomicAdd(&counts[col], 1);
}

// single block, 1024 threads, 16 elems each -> exclusive scan of 16384 counts
__global__ void scan_kernel(const int* __restrict__ counts, int* __restrict__ col_start) {
    __shared__ int sums[1024];
    int t = threadIdx.x;
    int base = t * 16;
    int local[16];
    int run = 0;
    for (int i = 0; i < 16; ++i) { local[i] = run; run += counts[base + i]; }
    sums[t] = run;
    __syncthreads();
    for (int off = 1; off < 1024; off <<= 1) {
        int v = (t >= off) ? sums[t - off] : 0;
        __syncthreads();
        sums[t] += v;
        __syncthreads();
    }
    int prev = (t == 0) ? 0 : sums[t - 1];
    for (int i = 0; i < 16; ++i) col_start[base + i] = prev + local[i];
    if (t == 1023) col_start[N] = prev + run;
}

__global__ void copy_cursor_kernel(const int* __restrict__ col_start, int* __restrict__ cursor) {
    int i = blockIdx.x * 256 + threadIdx.x;
    cursor[i] = col_start[i];
}

__global__ void scatter_kernel(const int* __restrict__ w, const float* __restrict__ kern,
                               const int* __restrict__ flag, int* __restrict__ cursor,
                               int* __restrict__ perm_rows, float* __restrict__ perm_vals) {
    int k = blockIdx.x * 256 + threadIdx.x;
    int is64 = *flag;
    int row = dec_row(w, k, is64);
    int col = dec_col(w, k, is64);
    int pos = atomicAdd(&cursor[col], 1);
    perm_rows[pos] = row;
    perm_vals[pos] = kern[k];
}

// ---------- transpose (rows x cols) -> (cols x rows), dims multiples of 32 ----------
__global__ void transpose_kernel(const float* __restrict__ in, float* __restrict__ out,
                                 int rows, int cols) {
    __shared__ float tile[32][33];
    int bx = blockIdx.x * 32;   // col offset in `in`
    int by = blockIdx.y * 32;   // row offset in `in`
    int tx = threadIdx.x, ty = threadIdx.y;   // 32 x 8
    for (int i = 0; i < 32; i += 8)
        tile[ty + i][tx] = in[(size_t)(by + ty + i) * cols + (bx + tx)];
    __syncthreads();
    for (int i = 0; i < 32; i += 8)
        out[(size_t)(bx + ty + i) * rows + (by + tx)] = tile[tx][ty + i];
}

// ---------- fused spmm + LSTM gates, one block per output column ----------
__global__ __launch_bounds__(256) void lstm_iter_kernel(
        const float* __restrict__ h_old,   // (N,B)
        float*       __restrict__ h_new,   // (N,B)
        float*       __restrict__ c,       // (N,B) in-place
        const int*   __restrict__ col_start,
        const int*   __restrict__ rows,
        const float* __restrict__ vals,
        const float* __restrict__ bi_, const float* __restrict__ bf_,
        const float* __restrict__ bo_, const float* __restrict__ bg_) {
    int col = blockIdx.x;
    int t = threadIdx.x;                 // 256 threads, float2 each -> B=512
    int s = col_start[col];
    int e = col_start[col + 1];
    const float2* h2 = (const float2*)h_old;

    float zx = 0.f, zy = 0.f;
    for (int k = s; k < e; ++k) {
        int   r = rows[k];
        float v = vals[k];
        float2 hv = h2[(size_t)r * (B / 2) + t];
        zx = fmaf(v, hv.x, zx);
        zy = fmaf(v, hv.y, zy);
    }

    float bi = bi_[col], bf = bf_[col], bo = bo_[col], bg = bg_[col];
    size_t idx = (size_t)col * (B / 2) + t;
    float2 cv = ((const float2*)c)[idx];

    float i0 = sigmoid_(zx + bi), f0 = sigmoid_(zx + bf);
    float o0 = sigmoid_(zx + bo), g0 = tanh_(zx + bg);
    float cx = f0 * cv.x + i0 * g0;
    float hx = o0 * tanh_(cx);

    float i1 = sigmoid_(zy + bi), f1 = sigmoid_(zy + bf);
    float o1 = sigmoid_(zy + bo), g1 = tanh_(zy + bg);
    float cy = f1 * cv.y + i1 * g1;
    float hy = o1 * tanh_(cy);

    ((float2*)c)[idx]     = make_float2(cx, cy);
    ((float2*)h_new)[idx] = make_float2(hx, hy);
}

extern "C" void kernel_launch(void* const* d_in, const int* in_sizes, int n_in,
                              void* d_out, int out_size, void* d_ws, size_t ws_size,
                              hipStream_t stream) {
    const float* x    = (const float*)d_in[0];
    const float* kern = (const float*)d_in[1];
    const float* b_i  = (const float*)d_in[2];
    const float* b_f  = (const float*)d_in[3];
    const float* b_o  = (const float*)d_in[4];
    const float* b_g  = (const float*)d_in[5];
    const int*   idxw = (const int*)d_in[6];

    char* ws = (char*)d_ws;
    // layout (bytes):
    float* hA        = (float*)(ws + 0);            // 33554432
    float* c         = (float*)(ws + 33554432);     // 33554432
    int*   perm_rows = (int*)  (ws + 67108864);     // 524288
    float* perm_vals = (float*)(ws + 67633152);     // 524288
    int*   col_start = (int*)  (ws + 68157440);     // (N+1)*4
    int*   cursor    = (int*)  (ws + 68224000);     // N*4
    int*   counts    = (int*)  (ws + 68289536);     // N*4
    int*   flag      = (int*)  (ws + 68355072);     // 4
    float* hB        = (float*)d_out;               // scratch until final transpose

    hipMemsetAsync(c, 0, (size_t)N * B * sizeof(float), stream);
    hipMemsetAsync(counts, 0, N * sizeof(int), stream);

    detect_kernel<<<1, 64, 0, stream>>>(idxw, flag);
    hist_kernel<<<NNZ / 256, 256, 0, stream>>>(idxw, flag, counts);
    scan_kernel<<<1, 1024, 0, stream>>>(counts, col_start);
    copy_cursor_kernel<<<N / 256, 256, 0, stream>>>(col_start, cursor);
    scatter_kernel<<<NNZ / 256, 256, 0, stream>>>(idxw, kern, flag, cursor,
                                                  perm_rows, perm_vals);

    // xT : (B,N) -> (N,B)
    transpose_kernel<<<dim3(N / 32, B / 32), dim3(32, 8), 0, stream>>>(x, hA, B, N);

    float* hin = hA;
    float* hout = hB;
    for (int it = 0; it < NITER; ++it) {
        lstm_iter_kernel<<<N, 256, 0, stream>>>(hin, hout, c, col_start,
                                                perm_rows, perm_vals,
                                                b_i, b_f, b_o, b_g);
        float* tmp = hin; hin = hout; hout = tmp;
    }
    // after 4 iterations the final h sits in hA; transpose (N,B) -> (B,N) into d_out
    transpose_kernel<<<dim3(B / 32, N / 32), dim3(32, 8), 0, stream>>>(hA, (float*)d_out, N, B);
}